// Round 3
// baseline (133.963 us; speedup 1.0000x reference)
//
#include <hip/hip_runtime.h>
#include <math.h>

#define BATCH 32
#define H 512
#define W 512
#define PAD 15
#define R 4                         /* output rows per wave */
#define BANDS (H / R)               /* 128 */
#define NWAVES (BATCH * BANDS)      /* 4096 */
#define WPB 4                       /* waves per block */
#define NBLOCKS (NWAVES / WPB)      /* 1024 */
#define INV_KK (1.0f / 961.0f)

__device__ __forceinline__ void load_row8(const float* __restrict__ base, float rv[8]) {
    const float4* p = (const float4*)base;
    float4 a = p[0], b = p[1];
    rv[0] = a.x; rv[1] = a.y; rv[2] = a.z; rv[3] = a.w;
    rv[4] = b.x; rv[5] = b.y; rv[6] = b.z; rv[7] = b.w;
}

__global__ __launch_bounds__(WPB * 64, 4)
void wbce_wave_kernel(const float* __restrict__ logits,
                      const float* __restrict__ targets,
                      float* __restrict__ partials) {
    __shared__ float rn[WPB], rd[WPB];

    const int tid  = threadIdx.x;
    const int lane = tid & 63;
    const int w    = tid >> 6;
    const int wid  = blockIdx.x * WPB + w;
    const int img  = wid >> 7;            /* wid / BANDS */
    const int band = wid & (BANDS - 1);
    const int y0   = band * R;
    const int x0   = lane * 8;

    const float* tb = targets + (size_t)img * H * W;
    const float* lb = logits  + (size_t)img * H * W;

    /* ---- Phase A: vertical window sums, all loads independent ---- */
    float vs[R][8];
    #pragma unroll
    for (int j = 0; j < R; ++j)
        #pragma unroll
        for (int k = 0; k < 8; ++k) vs[j][k] = 0.f;

    #pragma unroll
    for (int dy = -PAD; dy <= PAD; ++dy) {
        int y = y0 + dy;
        float rv[8] = {0, 0, 0, 0, 0, 0, 0, 0};
        if (y >= 0 && y < H) load_row8(tb + (size_t)y * W + x0, rv);
        #pragma unroll
        for (int k = 0; k < 8; ++k) vs[0][k] += rv[k];
    }
    {
        float ra[3][8], rs[3][8];
        #pragma unroll
        for (int d = 0; d < 3; ++d) {
            int ya = y0 + PAD + 1 + d;     /* entering rows 16,17,18 */
            int ys = y0 - PAD + d;         /* leaving rows -15,-14,-13 */
            #pragma unroll
            for (int k = 0; k < 8; ++k) { ra[d][k] = 0.f; rs[d][k] = 0.f; }
            if (ya < H)  load_row8(tb + (size_t)ya * W + x0, ra[d]);
            if (ys >= 0) load_row8(tb + (size_t)ys * W + x0, rs[d]);
        }
        #pragma unroll
        for (int d = 0; d < 3; ++d)
            #pragma unroll
            for (int k = 0; k < 8; ++k)
                vs[d + 1][k] = vs[d][k] + ra[d][k] - rs[d][k];
    }

    /* ---- Phase B: horizontal 31-sum via segment sums (no scan chain) ---- */
    const bool okm2 = lane >= 2, okm1 = lane >= 1;
    const bool okp1 = lane <= 62, okp2 = lane <= 61;
    float num = 0.f, den = 0.f;

    #pragma unroll
    for (int j = 0; j < R; ++j) {
        const int y = y0 + j;

        float p[8];
        p[0] = vs[j][0];
        #pragma unroll
        for (int k = 1; k < 8; ++k) p[k] = p[k - 1] + vs[j][k];
        const float tot = p[7];

        float pm2[8], pe[7];
        #pragma unroll
        for (int k = 0; k < 8; ++k) pm2[k] = __shfl_up(p[k], 2);
        #pragma unroll
        for (int k = 0; k < 7; ++k) pe[k] = __shfl_down(p[k], 2);
        const float bm = __shfl_up(tot, 1);
        const float dp = __shfl_down(tot, 1);
        const float base = (okm1 ? bm : 0.f) + tot + (okp1 ? dp : 0.f);

        float tv[8], lv[8];
        load_row8(tb + (size_t)y * W + x0, tv);
        load_row8(lb + (size_t)y * W + x0, lv);

        #pragma unroll
        for (int k = 0; k < 8; ++k) {
            float a  = okm2 ? (pm2[7] - pm2[k]) : 0.f;
            float e  = (k >= 1 && okp2) ? pe[k - 1] : 0.f;
            float hs = a + base + e;
            float pooled = hs * INV_KK;
            float wgt = fmaf(5.f, fabsf(pooled - tv[k]), 1.f);
            float al  = fabsf(lv[k]);
            float bce = fmaxf(lv[k], 0.f) - lv[k] * tv[k]
                        + __logf(1.f + __expf(-al));
            num = fmaf(wgt, bce, num);
            den += wgt;
        }
    }

    /* ---- wave + block reduction, one partial pair per block ---- */
    #pragma unroll
    for (int off = 32; off > 0; off >>= 1) {
        num += __shfl_down(num, off);
        den += __shfl_down(den, off);
    }
    if (lane == 0) { rn[w] = num; rd[w] = den; }
    __syncthreads();
    if (tid == 0) {
        float n = 0.f, d = 0.f;
        #pragma unroll
        for (int i = 0; i < WPB; ++i) { n += rn[i]; d += rd[i]; }
        partials[blockIdx.x * 2]     = n;
        partials[blockIdx.x * 2 + 1] = d;
    }
}

/* 1024 partial pairs -> scalar. Image i owns pairs [i*32, i*32+32). */
__global__ __launch_bounds__(1024)
void wbce_finalize_kernel(const float* __restrict__ partials,
                          float* __restrict__ out) {
    __shared__ float rsum[16];
    const int t = threadIdx.x;
    float num = partials[t * 2];
    float den = partials[t * 2 + 1];
    #pragma unroll
    for (int off = 16; off > 0; off >>= 1) {
        num += __shfl_down(num, off, 32);
        den += __shfl_down(den, off, 32);
    }
    float ratio = 0.f;
    if ((t & 31) == 0) ratio = num / den;
    ratio += __shfl_down(ratio, 32);          /* lane0 += lane32 */
    const int lane = t & 63;
    const int wv = t >> 6;
    if (lane == 0) rsum[wv] = ratio;
    __syncthreads();
    if (t == 0) {
        float s = 0.f;
        #pragma unroll
        for (int i = 0; i < 16; ++i) s += rsum[i];
        out[0] = s / (float)BATCH;
    }
}

extern "C" void kernel_launch(void* const* d_in, const int* in_sizes, int n_in,
                              void* d_out, int out_size, void* d_ws, size_t ws_size,
                              hipStream_t stream) {
    const float* logits  = (const float*)d_in[0];
    const float* targets = (const float*)d_in[1];
    float* out = (float*)d_out;
    float* partials = (float*)d_ws;   /* NBLOCKS*2 floats = 8 KB */

    wbce_wave_kernel<<<NBLOCKS, WPB * 64, 0, stream>>>(logits, targets, partials);
    wbce_finalize_kernel<<<1, 1024, 0, stream>>>(partials, out);
}